// Round 13
// baseline (199.120 us; speedup 1.0000x reference)
//
#include <hip/hip_runtime.h>
#include <math.h>

#define NDIMS 32
#define NANG 496          // 32*31/2
#define MPB 8             // matrices per gen_R block
#define BCOLS 128         // columns per block (64 lanes * 2 cols)

typedef float f32x4 __attribute__((ext_vector_type(4)));
typedef float f32x2 __attribute__((ext_vector_type(2)));

// ---------------- Kernel 1: build R^T (mus folded) into workspace ----------
// RTbuf[m][k][i] = mus[m][i] * R[i][k]   ([k][i] layout)
__global__ __launch_bounds__(256)
void gen_R(const float* __restrict__ angles, const float* __restrict__ mus,
           float* __restrict__ RT)
{
    __shared__ float2 cs[MPB][NANG];      // 31744 B
    const int tid = threadIdx.x;
    const int m0  = blockIdx.x * MPB;

    for (int idx = tid; idx < MPB * NANG; idx += 256) {
        const int lm = idx / NANG, a = idx - lm * NANG;
        float sv, cv;
        sincosf(angles[(size_t)(m0 + lm) * NANG + a], &sv, &cv);
        cs[lm][a] = make_float2(cv, sv);
    }
    __syncthreads();

    const int lm = tid >> 5, j = tid & 31;   // lane j owns column j of mat[m]
    const int m  = m0 + lm;

    float r[NDIMS];
    #pragma unroll
    for (int i = 0; i < NDIMS; ++i) r[i] = (i == j) ? 1.0f : 0.0f;

    int sidx = 0;
    #pragma unroll
    for (int t = 0; t < NDIMS - 1; ++t) {
        #pragma unroll
        for (int b = t + 1; b < NDIMS; ++b) {
            const float2 v = cs[lm][sidx]; ++sidx;   // compile-time sidx
            const float c = v.x, sn = v.y;
            const float vt = r[t], vb = r[b];
            const float u  = sn * (vt + vb);
            r[t] = (c + sn) * vt - u;
            r[b] = (c - sn) * vb + u;
        }
    }

    // RT[m][k=j][i] = r[i] * mu[i]
    float* dst = RT + (size_t)m * (NDIMS * NDIMS) + (size_t)j * NDIMS;
    const float* mu = mus + (size_t)m * NDIMS;
    #pragma unroll
    for (int i = 0; i < NDIMS; i += 4) {
        f32x4 v;
        v.x = r[i + 0] * mu[i + 0];
        v.y = r[i + 1] * mu[i + 1];
        v.z = r[i + 2] * mu[i + 2];
        v.w = r[i + 3] * mu[i + 3];
        *reinterpret_cast<f32x4*>(dst + i) = v;
    }
}

// ---------------- Kernel 2: out = R*x, MAX-OCCUPANCY streaming -------------
// R10-R12 post-mortem: every LDS-staged/pipelined variant converged to
// ~140us at 2-4 blocks/CU; R10 counters showed a CONCURRENCY wall (2.35 TB/s
// at 10.8% occupancy, x is L3-resident), not a BW wall. This kernel removes
// the machinery: per-thread state = acc[8] f32x2 (16 VGPR) only; rt (4 KB)
// is the only LDS; no barriers in the k-loop; loads are per-k f32x2 at
// uniform-SGPR-base + one divergent voffset. Natural VGPR ~50 -> cap 64 via
// __launch_bounds__(256,8) WITHOUT spilling -> 8 waves/SIMD, 32 waves/CU.
// Latency hiding by TLP: 32 waves x ~2 loads in flight x 512B ~= 32KB/CU
// outstanding. 4 row-group waves re-read the same x columns -> L1/L2-served
// (x fits in L3; HBM traffic unchanged).
__global__ __launch_bounds__(256, 8)
void apply_S1(const float* __restrict__ x, const float* __restrict__ RT,
              float* __restrict__ out, int S)
{
    __shared__ float rt[NDIMS * NDIMS];   // [k][i], 4 KB
    const int tid = threadIdx.x;
    const int m   = blockIdx.x;

    // stage R^T (4 KB): 256 threads x 16 B
    *reinterpret_cast<f32x4*>(&rt[tid * 4]) =
        *reinterpret_cast<const f32x4*>(RT + (size_t)m * (NDIMS * NDIMS) + tid * 4);
    __syncthreads();

    const int wid  = tid >> 6;            // wave id = row group (0..3)
    const int lane = tid & 63;
    const int i0   = wid * 8;
    const int col  = blockIdx.y * BCOLS + lane * 2;

    const float* __restrict__ xm = x   + (size_t)m * NDIMS * S;
    float*       __restrict__ om = out + (size_t)m * NDIMS * S;

    f32x2 acc[8];
    #pragma unroll
    for (int r = 0; r < 8; ++r) acc[r] = (f32x2)0.0f;

    #pragma unroll 2
    for (int k = 0; k < NDIMS; ++k) {
        const f32x2 xv = *reinterpret_cast<const f32x2*>(xm + (size_t)k * S + col);
        const f32x4 ra = *reinterpret_cast<const f32x4*>(&rt[k * NDIMS + i0]);     // broadcast
        const f32x4 rb = *reinterpret_cast<const f32x4*>(&rt[k * NDIMS + i0 + 4]); // broadcast
        acc[0].x = fmaf(ra.x, xv.x, acc[0].x);  acc[0].y = fmaf(ra.x, xv.y, acc[0].y);
        acc[1].x = fmaf(ra.y, xv.x, acc[1].x);  acc[1].y = fmaf(ra.y, xv.y, acc[1].y);
        acc[2].x = fmaf(ra.z, xv.x, acc[2].x);  acc[2].y = fmaf(ra.z, xv.y, acc[2].y);
        acc[3].x = fmaf(ra.w, xv.x, acc[3].x);  acc[3].y = fmaf(ra.w, xv.y, acc[3].y);
        acc[4].x = fmaf(rb.x, xv.x, acc[4].x);  acc[4].y = fmaf(rb.x, xv.y, acc[4].y);
        acc[5].x = fmaf(rb.y, xv.x, acc[5].x);  acc[5].y = fmaf(rb.y, xv.y, acc[5].y);
        acc[6].x = fmaf(rb.z, xv.x, acc[6].x);  acc[6].y = fmaf(rb.z, xv.y, acc[6].y);
        acc[7].x = fmaf(rb.w, xv.x, acc[7].x);  acc[7].y = fmaf(rb.w, xv.y, acc[7].y);
    }

    // stores: per row, wave writes 512 B contiguous (dwordx2 per lane)
    #pragma unroll
    for (int r = 0; r < 8; ++r)
        *reinterpret_cast<f32x2*>(om + (size_t)(i0 + r) * S + col) = acc[r];
}

// ---------------- Fallback: fused kernel (odd sizes / tiny ws) -------------
#define RT_STRIDE 36
__global__ __launch_bounds__(256, 4)
void soot_fused(const float* __restrict__ x, const float* __restrict__ angles,
                const float* __restrict__ mus, float* __restrict__ out, int S)
{
    __shared__ float2 cs[NANG];
    __shared__ float  RT[NDIMS * RT_STRIDE];
    const int tid = threadIdx.x;
    const int m   = blockIdx.x;

    for (int s0 = tid; s0 < NANG; s0 += 256) {
        float sv, cv;
        sincosf(angles[(size_t)m * NANG + s0], &sv, &cv);
        cs[s0] = make_float2(cv, sv);
    }
    __syncthreads();

    if (tid < NDIMS) {
        const int j = tid;
        float r[NDIMS];
        #pragma unroll
        for (int i = 0; i < NDIMS; ++i) r[i] = (i == j) ? 1.0f : 0.0f;
        int sidx = 0;
        #pragma unroll
        for (int t = 0; t < NDIMS - 1; ++t)
            #pragma unroll
            for (int b = t + 1; b < NDIMS; ++b) {
                const float2 v = cs[sidx]; ++sidx;
                const float c = v.x, sn = v.y;
                const float vt = r[t], vb = r[b];
                const float u  = sn * (vt + vb);
                r[t] = (c + sn) * vt - u;
                r[b] = (c - sn) * vb + u;
            }
        #pragma unroll
        for (int i = 0; i < NDIMS; ++i)
            RT[j * RT_STRIDE + i] = r[i] * mus[(size_t)m * NDIMS + i];
    }
    __syncthreads();

    for (int c0 = tid; c0 < S; c0 += 256) {
        float acc[NDIMS];
        #pragma unroll
        for (int i = 0; i < NDIMS; ++i) acc[i] = 0.f;
        #pragma unroll
        for (int k = 0; k < NDIMS; ++k) {
            const float xv = x[(size_t)m * NDIMS * S + (size_t)k * S + c0];
            #pragma unroll
            for (int i = 0; i < NDIMS; ++i)
                acc[i] = fmaf(RT[k * RT_STRIDE + i], xv, acc[i]);
        }
        #pragma unroll
        for (int i = 0; i < NDIMS; ++i)
            out[(size_t)m * NDIMS * S + (size_t)i * S + c0] = acc[i];
    }
}

extern "C" void kernel_launch(void* const* d_in, const int* in_sizes, int n_in,
                              void* d_out, int out_size, void* d_ws, size_t ws_size,
                              hipStream_t stream) {
    const float* x      = (const float*)d_in[0];
    const float* angles = (const float*)d_in[1];
    const float* mus    = (const float*)d_in[2];
    float* out          = (float*)d_out;

    const int M = in_sizes[1] / NANG;              // 1024
    const int S = in_sizes[0] / (M * NDIMS);       // 2048

    const size_t rt_bytes = (size_t)M * NDIMS * NDIMS * sizeof(float);  // 4 MB
    if (ws_size >= rt_bytes && (M % MPB) == 0 && (S % BCOLS) == 0) {
        float* RT = (float*)d_ws;
        gen_R<<<dim3(M / MPB), 256, 0, stream>>>(angles, mus, RT);
        dim3 grid(M, S / BCOLS);
        apply_S1<<<grid, 256, 0, stream>>>(x, RT, out, S);
    } else {
        soot_fused<<<dim3(M), 256, 0, stream>>>(x, angles, mus, out, S);
    }
}

// Round 14
// 116.563 us; speedup vs baseline: 1.7083x; 1.7083x over previous
//
#include <hip/hip_runtime.h>
#include <math.h>

#define NDIMS 32
#define NANG 496          // 32*31/2
#define MPB 4             // matrices per gen_R block (128 threads)
#define TCOLS 128         // columns per apply block

typedef float f32x4 __attribute__((ext_vector_type(4)));
typedef float f32x2 __attribute__((ext_vector_type(2)));

// async 16B/lane global -> LDS (dest: wave-uniform base, HW adds lane*16;
// src: per-lane address)
__device__ __forceinline__ void load16_to_lds(const float* gsrc, float* ldst) {
    __builtin_amdgcn_global_load_lds(
        (const __attribute__((address_space(1))) void*)gsrc,
        (__attribute__((address_space(3))) void*)ldst,
        16, 0, 0);
}

// ---------------- Kernel 1: build R^T (mus folded) into workspace ----------
// RTbuf[m][k][i] = mus[m][i] * R[i][k]   ([k][i] layout)
__global__ __launch_bounds__(128)
void gen_R(const float* __restrict__ angles, const float* __restrict__ mus,
           float* __restrict__ RT)
{
    __shared__ float2 cs[MPB][NANG];      // 15872 B
    const int tid = threadIdx.x;
    const int m0  = blockIdx.x * MPB;

    for (int idx = tid; idx < MPB * NANG; idx += 128) {
        const int lm = idx / NANG, a = idx - lm * NANG;
        float sv, cv;
        sincosf(angles[(size_t)(m0 + lm) * NANG + a], &sv, &cv);
        cs[lm][a] = make_float2(cv, sv);
    }
    __syncthreads();

    const int lm = tid >> 5, j = tid & 31;   // lane j owns column j of mat[m]
    const int m  = m0 + lm;

    float r[NDIMS];
    #pragma unroll
    for (int i = 0; i < NDIMS; ++i) r[i] = (i == j) ? 1.0f : 0.0f;

    int sidx = 0;
    #pragma unroll
    for (int t = 0; t < NDIMS - 1; ++t) {
        #pragma unroll
        for (int b = t + 1; b < NDIMS; ++b) {
            const float2 v = cs[lm][sidx]; ++sidx;   // compile-time sidx
            const float c = v.x, sn = v.y;
            const float vt = r[t], vb = r[b];
            const float u  = sn * (vt + vb);
            r[t] = (c + sn) * vt - u;
            r[b] = (c - sn) * vb + u;
        }
    }

    // RT[m][k=j][i] = r[i] * mu[i]
    float* dst = RT + (size_t)m * (NDIMS * NDIMS) + (size_t)j * NDIMS;
    const float* mu = mus + (size_t)m * NDIMS;
    #pragma unroll
    for (int i = 0; i < NDIMS; i += 4) {
        f32x4 v;
        v.x = r[i + 0] * mu[i + 0];
        v.y = r[i + 1] * mu[i + 1];
        v.z = r[i + 2] * mu[i + 2];
        v.w = r[i + 3] * mu[i + 3];
        *reinterpret_cast<f32x4*>(dst + i) = v;
    }
}

// ---------------- Kernel 2: LDS-staged, 8 blocks/CU ------------------------
// Ledger: R11's stage->barrier->compute (4 blocks/CU, VGPR<=128) = 129us is
// the best; R13 proved raw occupancy isn't the fix (83% occ, 180us: per-wave
// MLP too shallow for L3-latency loads). This kernel keeps the only load
// path that buys MLP without VGPRs (global_load_lds) and doubles residency:
// LDS = rt 4KB + xt 16KB = 20KB -> 8 blocks/CU (160KB exact), acc = f32x2 x8
// = 16 VGPR, cap 64 via __launch_bounds__(256,8) -> 8 waves/SIMD. 7 blocks
// stage behind 1 computing. Stores are nontemporal so `out` doesn't evict
// x from L3.
__global__ __launch_bounds__(256, 8)
void apply_T1(const float* __restrict__ x, const float* __restrict__ RT,
              float* __restrict__ out, int S)
{
    __shared__ float rt[NDIMS * NDIMS];   // [k][i], 4 KB
    __shared__ float xt[NDIMS][TCOLS];    // [k][col], 16 KB

    const int tid  = threadIdx.x;
    const int m    = blockIdx.x;
    const int wid  = tid >> 6;            // wave id, 0..3
    const int lane = tid & 63;
    const int col0 = blockIdx.y * TCOLS;

    const float* __restrict__ xm = x   + (size_t)m * NDIMS * S + col0;
    float*       __restrict__ om = out + (size_t)m * NDIMS * S + col0;

    // stage R^T (4 KB): 256 threads x 16 B
    *reinterpret_cast<f32x4*>(&rt[tid * 4]) =
        *reinterpret_cast<const f32x4*>(RT + (size_t)m * (NDIMS * NDIMS) + tid * 4);

    // stage x tile (16 KB = 32 rows x 512 B) async: one width-16 instr
    // stages TWO rows (lanes 32-63 land at dest+512B = row k+1).
    // Wave wid stages rows {wid*8 .. wid*8+7} as 4 instrs.
    const size_t srcRow = (size_t)(lane >> 5) * S + (lane & 31) * 4;
    #pragma unroll
    for (int p = 0; p < 4; ++p) {
        const int k = wid * 8 + p * 2;
        load16_to_lds(xm + (size_t)k * S + srcRow, &xt[k][0]);
    }
    __syncthreads();   // drains vmcnt+lgkmcnt

    const int i0 = wid * 8;               // this wave's 8 output rows

    f32x2 acc[8];
    #pragma unroll
    for (int r = 0; r < 8; ++r) acc[r] = (f32x2)0.0f;

    #pragma unroll 2
    for (int k = 0; k < NDIMS; ++k) {
        const f32x2 xv = *reinterpret_cast<const f32x2*>(&xt[k][lane * 2]);        // lane-unique b64
        const f32x4 ra = *reinterpret_cast<const f32x4*>(&rt[k * NDIMS + i0]);     // broadcast b128
        const f32x4 rb = *reinterpret_cast<const f32x4*>(&rt[k * NDIMS + i0 + 4]); // broadcast b128
        acc[0].x = fmaf(ra.x, xv.x, acc[0].x);  acc[0].y = fmaf(ra.x, xv.y, acc[0].y);
        acc[1].x = fmaf(ra.y, xv.x, acc[1].x);  acc[1].y = fmaf(ra.y, xv.y, acc[1].y);
        acc[2].x = fmaf(ra.z, xv.x, acc[2].x);  acc[2].y = fmaf(ra.z, xv.y, acc[2].y);
        acc[3].x = fmaf(ra.w, xv.x, acc[3].x);  acc[3].y = fmaf(ra.w, xv.y, acc[3].y);
        acc[4].x = fmaf(rb.x, xv.x, acc[4].x);  acc[4].y = fmaf(rb.x, xv.y, acc[4].y);
        acc[5].x = fmaf(rb.y, xv.x, acc[5].x);  acc[5].y = fmaf(rb.y, xv.y, acc[5].y);
        acc[6].x = fmaf(rb.z, xv.x, acc[6].x);  acc[6].y = fmaf(rb.z, xv.y, acc[6].y);
        acc[7].x = fmaf(rb.w, xv.x, acc[7].x);  acc[7].y = fmaf(rb.w, xv.y, acc[7].y);
    }

    // stores: per row, wave writes 512 B contiguous; nontemporal (write-once,
    // keep x resident in L3)
    #pragma unroll
    for (int r = 0; r < 8; ++r)
        __builtin_nontemporal_store(acc[r],
            reinterpret_cast<f32x2*>(om + (size_t)(i0 + r) * S + lane * 2));
}

// ---------------- Fallback: fused kernel (odd sizes / tiny ws) -------------
#define RT_STRIDE 36
__global__ __launch_bounds__(256, 4)
void soot_fused(const float* __restrict__ x, const float* __restrict__ angles,
                const float* __restrict__ mus, float* __restrict__ out, int S)
{
    __shared__ float2 cs[NANG];
    __shared__ float  RT[NDIMS * RT_STRIDE];
    const int tid = threadIdx.x;
    const int m   = blockIdx.x;

    for (int s0 = tid; s0 < NANG; s0 += 256) {
        float sv, cv;
        sincosf(angles[(size_t)m * NANG + s0], &sv, &cv);
        cs[s0] = make_float2(cv, sv);
    }
    __syncthreads();

    if (tid < NDIMS) {
        const int j = tid;
        float r[NDIMS];
        #pragma unroll
        for (int i = 0; i < NDIMS; ++i) r[i] = (i == j) ? 1.0f : 0.0f;
        int sidx = 0;
        #pragma unroll
        for (int t = 0; t < NDIMS - 1; ++t)
            #pragma unroll
            for (int b = t + 1; b < NDIMS; ++b) {
                const float2 v = cs[sidx]; ++sidx;
                const float c = v.x, sn = v.y;
                const float vt = r[t], vb = r[b];
                const float u  = sn * (vt + vb);
                r[t] = (c + sn) * vt - u;
                r[b] = (c - sn) * vb + u;
            }
        #pragma unroll
        for (int i = 0; i < NDIMS; ++i)
            RT[j * RT_STRIDE + i] = r[i] * mus[(size_t)m * NDIMS + i];
    }
    __syncthreads();

    for (int c0 = tid; c0 < S; c0 += 256) {
        float acc[NDIMS];
        #pragma unroll
        for (int i = 0; i < NDIMS; ++i) acc[i] = 0.f;
        #pragma unroll
        for (int k = 0; k < NDIMS; ++k) {
            const float xv = x[(size_t)m * NDIMS * S + (size_t)k * S + c0];
            #pragma unroll
            for (int i = 0; i < NDIMS; ++i)
                acc[i] = fmaf(RT[k * RT_STRIDE + i], xv, acc[i]);
        }
        #pragma unroll
        for (int i = 0; i < NDIMS; ++i)
            out[(size_t)m * NDIMS * S + (size_t)i * S + c0] = acc[i];
    }
}

extern "C" void kernel_launch(void* const* d_in, const int* in_sizes, int n_in,
                              void* d_out, int out_size, void* d_ws, size_t ws_size,
                              hipStream_t stream) {
    const float* x      = (const float*)d_in[0];
    const float* angles = (const float*)d_in[1];
    const float* mus    = (const float*)d_in[2];
    float* out          = (float*)d_out;

    const int M = in_sizes[1] / NANG;              // 1024
    const int S = in_sizes[0] / (M * NDIMS);       // 2048

    const size_t rt_bytes = (size_t)M * NDIMS * NDIMS * sizeof(float);  // 4 MB
    if (ws_size >= rt_bytes && (M % MPB) == 0 && (S % TCOLS) == 0) {
        float* RT = (float*)d_ws;
        gen_R<<<dim3(M / MPB), 128, 0, stream>>>(angles, mus, RT);
        dim3 grid(M, S / TCOLS);
        apply_T1<<<grid, 256, 0, stream>>>(x, RT, out, S);
    } else {
        soot_fused<<<dim3(M), 256, 0, stream>>>(x, angles, mus, out, S);
    }
}

// Round 15
// 114.464 us; speedup vs baseline: 1.7396x; 1.0183x over previous
//
#include <hip/hip_runtime.h>
#include <math.h>

#define NDIMS 32
#define NANG 496          // 32*31/2
#define MPB 4             // matrices per gen_R block (128 threads)
#define TCOLS 128         // columns per apply block

typedef float f32x4 __attribute__((ext_vector_type(4)));
typedef float f32x2 __attribute__((ext_vector_type(2)));

// async 16B/lane global -> LDS (dest: wave-uniform base, HW adds lane*16;
// src: per-lane address)
__device__ __forceinline__ void load16_to_lds(const float* gsrc, float* ldst) {
    __builtin_amdgcn_global_load_lds(
        (const __attribute__((address_space(1))) void*)gsrc,
        (__attribute__((address_space(3))) void*)ldst,
        16, 0, 0);
}

// ---------------- Kernel 1: build R^T (mus folded) into workspace ----------
// RTbuf[m][k][i] = mus[m][i] * R[i][k]   ([k][i] layout)
__global__ __launch_bounds__(128)
void gen_R(const float* __restrict__ angles, const float* __restrict__ mus,
           float* __restrict__ RT)
{
    __shared__ float2 cs[MPB][NANG];      // 15872 B
    const int tid = threadIdx.x;
    const int m0  = blockIdx.x * MPB;

    for (int idx = tid; idx < MPB * NANG; idx += 128) {
        const int lm = idx / NANG, a = idx - lm * NANG;
        float sv, cv;
        sincosf(angles[(size_t)(m0 + lm) * NANG + a], &sv, &cv);
        cs[lm][a] = make_float2(cv, sv);
    }
    __syncthreads();

    const int lm = tid >> 5, j = tid & 31;   // lane j owns column j of mat[m]
    const int m  = m0 + lm;

    float r[NDIMS];
    #pragma unroll
    for (int i = 0; i < NDIMS; ++i) r[i] = (i == j) ? 1.0f : 0.0f;

    int sidx = 0;
    #pragma unroll
    for (int t = 0; t < NDIMS - 1; ++t) {
        #pragma unroll
        for (int b = t + 1; b < NDIMS; ++b) {
            const float2 v = cs[lm][sidx]; ++sidx;   // compile-time sidx
            const float c = v.x, sn = v.y;
            const float vt = r[t], vb = r[b];
            const float u  = sn * (vt + vb);
            r[t] = (c + sn) * vt - u;
            r[b] = (c - sn) * vb + u;
        }
    }

    // RT[m][k=j][i] = r[i] * mu[i]
    float* dst = RT + (size_t)m * (NDIMS * NDIMS) + (size_t)j * NDIMS;
    const float* mu = mus + (size_t)m * NDIMS;
    #pragma unroll
    for (int i = 0; i < NDIMS; i += 4) {
        f32x4 v;
        v.x = r[i + 0] * mu[i + 0];
        v.y = r[i + 1] * mu[i + 1];
        v.z = r[i + 2] * mu[i + 2];
        v.w = r[i + 3] * mu[i + 3];
        *reinterpret_cast<f32x4*>(dst + i) = v;
    }
}

// ---------------- Kernel 2: LDS-staged, 8 blocks/CU, packed FMA ------------
// R14 (116.6us, best): global_load_lds staging + 8 blocks/CU + VGPR=28.
// R15 deltas: (1) inner product as f32x2 vector arithmetic -> v_pk_fma_f32,
// halving VALU instrs (16->8 per k); (2) rt staged via global_load_lds too
// (1 instr/wave, dest &rt[wid*256], no VGPR round-trip / lgkmcnt chain).
__global__ __launch_bounds__(256, 8)
void apply_T2(const float* __restrict__ x, const float* __restrict__ RT,
              float* __restrict__ out, int S)
{
    __shared__ float rt[NDIMS * NDIMS];   // [k][i], 4 KB
    __shared__ float xt[NDIMS][TCOLS];    // [k][col], 16 KB

    const int tid  = threadIdx.x;
    const int m    = blockIdx.x;
    const int wid  = tid >> 6;            // wave id, 0..3
    const int lane = tid & 63;
    const int col0 = blockIdx.y * TCOLS;

    const float* __restrict__ xm = x   + (size_t)m * NDIMS * S + col0;
    float*       __restrict__ om = out + (size_t)m * NDIMS * S + col0;

    // stage R^T (4 KB): one width-16 global_load_lds per wave
    // (wave wid covers floats [wid*256, wid*256+256): lane l -> +l*4)
    load16_to_lds(RT + (size_t)m * (NDIMS * NDIMS) + wid * 256 + lane * 4,
                  &rt[wid * 256]);

    // stage x tile (16 KB = 32 rows x 512 B) async: one width-16 instr
    // stages TWO rows (lanes 32-63 land at dest+512B = row k+1).
    // Wave wid stages rows {wid*8 .. wid*8+7} as 4 instrs.
    const size_t srcRow = (size_t)(lane >> 5) * S + (lane & 31) * 4;
    #pragma unroll
    for (int p = 0; p < 4; ++p) {
        const int k = wid * 8 + p * 2;
        load16_to_lds(xm + (size_t)k * S + srcRow, &xt[k][0]);
    }
    __syncthreads();   // drains vmcnt (all 5 gload_lds had max overlap)

    const int i0 = wid * 8;               // this wave's 8 output rows

    f32x2 acc[8];
    #pragma unroll
    for (int r = 0; r < 8; ++r) acc[r] = (f32x2)0.0f;

    #pragma unroll 2
    for (int k = 0; k < NDIMS; ++k) {
        const f32x2 xv = *reinterpret_cast<const f32x2*>(&xt[k][lane * 2]);        // lane-unique b64
        const f32x4 ra = *reinterpret_cast<const f32x4*>(&rt[k * NDIMS + i0]);     // broadcast b128
        const f32x4 rb = *reinterpret_cast<const f32x4*>(&rt[k * NDIMS + i0 + 4]); // broadcast b128
        // scalar*vector splat -> v_pk_fma_f32 (8 packed FMAs instead of 16)
        acc[0] += ra.x * xv;
        acc[1] += ra.y * xv;
        acc[2] += ra.z * xv;
        acc[3] += ra.w * xv;
        acc[4] += rb.x * xv;
        acc[5] += rb.y * xv;
        acc[6] += rb.z * xv;
        acc[7] += rb.w * xv;
    }

    // stores: per row, wave writes 512 B contiguous; nontemporal (write-once,
    // keep x resident in L3)
    #pragma unroll
    for (int r = 0; r < 8; ++r)
        __builtin_nontemporal_store(acc[r],
            reinterpret_cast<f32x2*>(om + (size_t)(i0 + r) * S + lane * 2));
}

// ---------------- Fallback: fused kernel (odd sizes / tiny ws) -------------
#define RT_STRIDE 36
__global__ __launch_bounds__(256, 4)
void soot_fused(const float* __restrict__ x, const float* __restrict__ angles,
                const float* __restrict__ mus, float* __restrict__ out, int S)
{
    __shared__ float2 cs[NANG];
    __shared__ float  RT[NDIMS * RT_STRIDE];
    const int tid = threadIdx.x;
    const int m   = blockIdx.x;

    for (int s0 = tid; s0 < NANG; s0 += 256) {
        float sv, cv;
        sincosf(angles[(size_t)m * NANG + s0], &sv, &cv);
        cs[s0] = make_float2(cv, sv);
    }
    __syncthreads();

    if (tid < NDIMS) {
        const int j = tid;
        float r[NDIMS];
        #pragma unroll
        for (int i = 0; i < NDIMS; ++i) r[i] = (i == j) ? 1.0f : 0.0f;
        int sidx = 0;
        #pragma unroll
        for (int t = 0; t < NDIMS - 1; ++t)
            #pragma unroll
            for (int b = t + 1; b < NDIMS; ++b) {
                const float2 v = cs[sidx]; ++sidx;
                const float c = v.x, sn = v.y;
                const float vt = r[t], vb = r[b];
                const float u  = sn * (vt + vb);
                r[t] = (c + sn) * vt - u;
                r[b] = (c - sn) * vb + u;
            }
        #pragma unroll
        for (int i = 0; i < NDIMS; ++i)
            RT[j * RT_STRIDE + i] = r[i] * mus[(size_t)m * NDIMS + i];
    }
    __syncthreads();

    for (int c0 = tid; c0 < S; c0 += 256) {
        float acc[NDIMS];
        #pragma unroll
        for (int i = 0; i < NDIMS; ++i) acc[i] = 0.f;
        #pragma unroll
        for (int k = 0; k < NDIMS; ++k) {
            const float xv = x[(size_t)m * NDIMS * S + (size_t)k * S + c0];
            #pragma unroll
            for (int i = 0; i < NDIMS; ++i)
                acc[i] = fmaf(RT[k * RT_STRIDE + i], xv, acc[i]);
        }
        #pragma unroll
        for (int i = 0; i < NDIMS; ++i)
            out[(size_t)m * NDIMS * S + (size_t)i * S + c0] = acc[i];
    }
}

extern "C" void kernel_launch(void* const* d_in, const int* in_sizes, int n_in,
                              void* d_out, int out_size, void* d_ws, size_t ws_size,
                              hipStream_t stream) {
    const float* x      = (const float*)d_in[0];
    const float* angles = (const float*)d_in[1];
    const float* mus    = (const float*)d_in[2];
    float* out          = (float*)d_out;

    const int M = in_sizes[1] / NANG;              // 1024
    const int S = in_sizes[0] / (M * NDIMS);       // 2048

    const size_t rt_bytes = (size_t)M * NDIMS * NDIMS * sizeof(float);  // 4 MB
    if (ws_size >= rt_bytes && (M % MPB) == 0 && (S % TCOLS) == 0) {
        float* RT = (float*)d_ws;
        gen_R<<<dim3(M / MPB), 128, 0, stream>>>(angles, mus, RT);
        dim3 grid(M, S / TCOLS);
        apply_T2<<<grid, 256, 0, stream>>>(x, RT, out, S);
    } else {
        soot_fused<<<dim3(M), 256, 0, stream>>>(x, angles, mus, out, S);
    }
}